// Round 18
// baseline (146.344 us; speedup 1.0000x reference)
//
#include <hip/hip_runtime.h>

#define HEADS 8
static constexpr int BSZ = 4;
static constexpr int CCH = 512;
static constexpr int NSP = 2304;   // 48*48
static constexpr int DH  = 64;     // head dim

typedef _Float16 f16x8 __attribute__((ext_vector_type(8)));
typedef float f32x4 __attribute__((ext_vector_type(4)));
typedef float f32x16 __attribute__((ext_vector_type(16)));
typedef int i32x4 __attribute__((ext_vector_type(4)));
typedef unsigned short u16;
typedef unsigned int u32;

__device__ __forceinline__ u16 f2h(float f) {
  _Float16 h = (_Float16)f;
  return __builtin_bit_cast(u16, h);
}

__device__ __forceinline__ float fexp2(float x) {
  return __builtin_amdgcn_exp2f(x);
}

__device__ __forceinline__ void gl_lds16(const void* g, void* l) {
  __builtin_amdgcn_global_load_lds(
      (const __attribute__((address_space(1))) u32*)g,
      (__attribute__((address_space(3))) u32*)l, 16, 0, 0);
}

// ------ kernel 1: fused input conversion (W fp32->fp16, x transpose) ----
// blocks [0,1024): weight convert (wsel = gid>>8). blocks [1024,2176):
// x (b,c,n) fp32 -> xT (b,n,c) fp16 via 64x64 LDS transpose tile.
// Branch is block-uniform -> __syncthreads in the else-path is safe.
__global__ __launch_bounds__(256) void k_cvt(const float* __restrict__ w0,
    const float* __restrict__ w1, const float* __restrict__ w2,
    const float* __restrict__ w3, u16* __restrict__ Wall,
    const float* __restrict__ x, u16* __restrict__ xT) {
  __shared__ u16 t[64][66];
  int gid = blockIdx.x;
  if (gid < 1024) {
    int wsel = gid >> 8, bx = gid & 255;
    const float* src = wsel == 0 ? w0 : wsel == 1 ? w1 : wsel == 2 ? w2 : w3;
    int i = (bx * 256 + threadIdx.x) * 4;
    float4 v = *(const float4*)(src + i);
    ushort4 o;
    o.x = f2h(v.x); o.y = f2h(v.y); o.z = f2h(v.z); o.w = f2h(v.w);
    *(ushort4*)(Wall + (size_t)wsel * CCH * CCH + i) = o;
  } else {
    int g2 = gid - 1024;
    int b = g2 / 288, rem = g2 % 288;
    int c0 = (rem / 36) * 64, n0 = (rem % 36) * 64;
    int col = threadIdx.x & 63, rb = threadIdx.x >> 6;
#pragma unroll
    for (int rr = 0; rr < 16; rr++) {
      int r = rr * 4 + rb;  // c-local
      t[r][col] = f2h(x[((size_t)b * CCH + c0 + r) * NSP + n0 + col]);
    }
    __syncthreads();
#pragma unroll
    for (int rr = 0; rr < 16; rr++) {
      int r = rr * 4 + rb;  // n-local
      xT[((size_t)b * NSP + n0 + r) * CCH + c0 + col] = t[col][r];
    }
  }
}

// ------- kernel 2: fused 4-way projection GEMM (Wq/Wk/Wv/Wsc) ----------
// R18: BK=32 DOUBLE-BUFFERED staging (attn-R12 loop shape: stage tile k+1
// while computing tile k, one drain barrier per iter) -- the old loop was
// fully serial (stage; drain; compute) and ate L2 latency every K-step.
// Buffers: [c][A 4096 | B 4096] u16, c in {0,1} = 32KB; stash reuse keeps
// LDS_Block_Size at 34816 (4 blocks/CU unchanged). Swizzle for 64B rows:
// cc = p ^ (row&3) ^ (((row>>2)&1)<<1) -> 2-way (free) b128 reads; read
// XOR is lane-constant (row&3 == lane&3 since f*16 = 0 mod 4).
// Q is pre-scaled by log2(e) so attention softmax can use raw exp2.
__global__ __launch_bounds__(256) void k_proj(const u16* __restrict__ Wall,
    const u16* __restrict__ xT, u16* __restrict__ Qo, u16* __restrict__ Ko,
    u16* __restrict__ Vo, float* __restrict__ SCo) {
  __shared__ u16 smem[17408];          // 2x[A|B] dbuf (16384) ; reused as stash[128][136]
  int z = blockIdx.z, b = z >> 2, wsel = z & 3;
  int o0 = blockIdx.y * 128, n0 = blockIdx.x * 128;
  int tid = threadIdx.x, lane = tid & 63, wv = tid >> 6;
  int wr = wv >> 1, wc = wv & 1;
  const u16* Asrc = Wall + (size_t)wsel * CCH * CCH + (size_t)o0 * CCH;
  const u16* Bsrc = xT + ((size_t)b * NSP + n0) * CCH;

  // staging pointers: 512 16B-chunks per matrix per tile; thread does
  // chunks ch1 = tid, ch2 = 256 + tid for A and B. row = ch>>2, p = ch&3.
  int ch1 = tid, ch2 = 256 + tid;
  int r1 = ch1 >> 2, r2 = ch2 >> 2;
  int cc1 = (ch1 & 3) ^ (r1 & 3) ^ (((r1 >> 2) & 1) << 1);
  int cc2 = (ch2 & 3) ^ (r2 & 3) ^ (((r2 >> 2) & 1) << 1);
  const u16* a1 = Asrc + (size_t)r1 * CCH + (cc1 << 3);
  const u16* a2 = Asrc + (size_t)r2 * CCH + (cc2 << 3);
  const u16* b1 = Bsrc + (size_t)r1 * CCH + (cc1 << 3);
  const u16* b2 = Bsrc + (size_t)r2 * CCH + (cc2 << 3);

#define PSTAGE(c)                                      \
  do {                                                 \
    gl_lds16(a1, smem + (c) * 8192 + ch1 * 8);         \
    gl_lds16(a2, smem + (c) * 8192 + ch2 * 8);         \
    gl_lds16(b1, smem + (c) * 8192 + 4096 + ch1 * 8);  \
    gl_lds16(b2, smem + (c) * 8192 + 4096 + ch2 * 8);  \
    a1 += 32; a2 += 32; b1 += 32; b2 += 32;            \
  } while (0)

  // lane-constant read swizzle offset (u16 units)
  int kx = (((lane >> 4) ^ (lane & 3) ^ (((lane >> 2) & 1) << 1)) << 3);
  f32x4 acc[4][4] = {};

#define PCOMPUTE(c)                                                          \
  do {                                                                       \
    const u16* Ab = smem + (c) * 8192;                                       \
    const u16* Bb = Ab + 4096;                                               \
    f16x8 af[4], bfr[4];                                                     \
    _Pragma("unroll")                                                        \
    for (int f = 0; f < 4; f++) {                                            \
      int orow = wr * 64 + f * 16 + (lane & 15);                             \
      int nrow = wc * 64 + f * 16 + (lane & 15);                             \
      af[f]  = *(const f16x8*)(Ab + orow * 32 + kx);                         \
      bfr[f] = *(const f16x8*)(Bb + nrow * 32 + kx);                         \
    }                                                                        \
    _Pragma("unroll")                                                        \
    for (int i = 0; i < 4; i++)                                              \
      _Pragma("unroll")                                                      \
      for (int j = 0; j < 4; j++)                                            \
        acc[i][j] = __builtin_amdgcn_mfma_f32_16x16x32_f16(af[i], bfr[j],    \
                                                           acc[i][j], 0, 0, 0); \
  } while (0)

  PSTAGE(0);                           // k-slice 0
  __syncthreads();
#pragma unroll 1
  for (int it = 0; it < 8; it++) {     // 16 k-slices of 32, x2 unrolled
    PSTAGE(1);                         // slice 2*it+1
    PCOMPUTE(0);                       // slice 2*it
    __syncthreads();
    if (it < 7) PSTAGE(0);             // slice 2*it+2
    PCOMPUTE(1);                       // slice 2*it+1
    __syncthreads();
  }

  if (wsel >= 2) {
#pragma unroll
    for (int i = 0; i < 4; i++)
#pragma unroll
      for (int j = 0; j < 4; j++)
#pragma unroll
        for (int r = 0; r < 4; r++) {
          int o = o0 + wr * 64 + i * 16 + ((lane >> 4) << 2) + r;
          int n = n0 + wc * 64 + j * 16 + (lane & 15);
          size_t idx = ((size_t)b * CCH + o) * NSP + n;
          if (wsel == 3) SCo[idx] = acc[i][j][r];
          else           Vo[idx]  = f2h(acc[i][j][r]);
        }
  } else {
    u16* stash = smem;  // [128 n][136 o]
    float qs = (wsel == 0) ? 1.4426950408889634f : 1.0f;  // fold log2e into Q
#pragma unroll
    for (int i = 0; i < 4; i++)
#pragma unroll
      for (int j = 0; j < 4; j++)
#pragma unroll
        for (int r = 0; r < 4; r++) {
          int ol = wr * 64 + i * 16 + ((lane >> 4) << 2) + r;
          int nl = wc * 64 + j * 16 + (lane & 15);
          stash[nl * 136 + ol] = f2h(acc[i][j][r] * qs);
        }
    __syncthreads();
    u16* dst = wsel ? Ko : Qo;
    int hl = tid >> 7, nn = tid & 127;
    int h = (o0 >> 6) + hl;
    size_t base = ((size_t)(b * HEADS + h) * NSP + n0 + nn) * DH;
#pragma unroll
    for (int c2 = 0; c2 < 8; c2++)
      *(int4*)(dst + base + c2 * 8) = *(const int4*)(stash + nn * 136 + hl * 64 + c2 * 8);
  }
#undef PSTAGE
#undef PCOMPUTE
}

// ------------------- kernel 3: flash attention + epilogue ---------------
// R12/R15/R17 configuration EXACTLY (93.7-94.0 us, reproduced 3x). Scheduler
// sweet spot: 512-thr blocks, 8 waves = 4 q-subtiles x 2 KV-parities;
// 32-row tiles double-buffered per parity in 32KB LDS; in-block merge;
// bh-major grid pins each head's KV to one XCD (FETCH 90->26MB).
// NO launch_bounds waves-per-EU arg (caps VGPRs + residency: R4/R6/R7).
__global__ __launch_bounds__(512) void k_attn(const u16* __restrict__ Qw,
    const u16* __restrict__ Kw, const u16* __restrict__ Vw,
    const float* __restrict__ gamma, float* __restrict__ out) {
  __shared__ u16 smem[17408];          // 32KB staging [tp][buf][K2048|V2048] + 2KB merge m/l
  int bh = blockIdx.x, qt = blockIdx.y;
  int b = bh >> 3, h = bh & 7;
  int tid = threadIdx.x, lane = tid & 63, wv = tid >> 6;
  int l31 = lane & 31, hi = lane >> 5;
  int qh = wv & 3, tp = wv >> 2;
  int gid = tid & 255;                 // id within parity group
  int q0w = qt * 128 + qh * 32;
  const u16* Ksrc = Kw + (size_t)bh * NSP * DH;
  const u16* Vsrc = Vw + ((size_t)b * CCH + h * DH) * NSP;
  u16* PB = smem + tp * 8192;          // this parity's staging (2 bufs x 4096)

  // --- staging pointers: 1 K-chunk + 1 V-chunk per thread, advance 64 rows ---
  int mk = gid >> 3, pk = gid & 7;
  const u16* kc = Ksrc + (tp * 32 + mk) * DH + ((pk ^ (mk & 7)) << 3);
  int dv = gid >> 2, pv = gid & 3;
  const u16* vc = Vsrc + (size_t)dv * NSP + tp * 32 + ((pv ^ ((dv >> 1) & 3)) << 3);

#define STAGE(c)                                   \
  do {                                             \
    gl_lds16(kc, PB + (c) * 4096 + gid * 8);       \
    gl_lds16(vc, PB + (c) * 4096 + 2048 + gid * 8);\
    kc += 64 * DH;                                 \
    vc += 64;                                      \
  } while (0)

  // --- hoisted LDS read offsets (u16 units) ---
  int kswz = l31 & 7, vswz = (l31 >> 1) & 3;
  int kro = l31 * 64;
  int ko[4], vo[2];
#pragma unroll
  for (int kd = 0; kd < 4; kd++) ko[kd] = ((2 * kd + hi) ^ kswz) << 3;
#pragma unroll
  for (int s = 0; s < 2; s++) vo[s] = ((2 * s + hi) ^ vswz) << 3;
  int vr0 = l31 * 32, vr1 = (32 + l31) * 32;

  // Q B-frags: lane holds Q[q0w + l31][d = 16*kd + 8*hi + j]  (pre-scaled by log2e)
  f16x8 qf[4];
  const u16* Qbase = Qw + ((size_t)bh * NSP + q0w + l31) * DH + hi * 8;
#pragma unroll
  for (int kd = 0; kd < 4; kd++)
    qf[kd] = *(const f16x8*)(Qbase + kd * 16);

  float mrun = -1e30f, lrun = 0.f;
  f32x16 acc0 = {}, acc1 = {};   // lane: d = dblk*32+l31, q(r) = (r&3)+8*(r>>2)+4*hi

#define COMPUTE(c)                                                           \
  do {                                                                       \
    const u16* Kc = PB + (c) * 4096;                                         \
    const u16* Vc = Kc + 2048;                                               \
    f32x16 s0 = {};                                                          \
    __builtin_amdgcn_s_setprio(1);                                           \
    _Pragma("unroll")                                                        \
    for (int kd = 0; kd < 4; kd++) {                                         \
      f16x8 k0 = *(const f16x8*)(Kc + kro + ko[kd]);                         \
      s0 = __builtin_amdgcn_mfma_f32_32x32x16_f16(k0, qf[kd], s0, 0, 0, 0);  \
    }                                                                        \
    __builtin_amdgcn_s_setprio(0);                                           \
    float m0a = fmaxf(fmaxf(s0[0], s0[1]), s0[2]);                           \
    float m0b = fmaxf(fmaxf(s0[3], s0[4]), s0[5]);                           \
    float m0c = fmaxf(fmaxf(s0[6], s0[7]), s0[8]);                           \
    float m0d = fmaxf(fmaxf(s0[9], s0[10]), s0[11]);                         \
    float m0e = fmaxf(fmaxf(s0[12], s0[13]), s0[14]);                        \
    float tm = fmaxf(fmaxf(fmaxf(m0a, m0b), fmaxf(m0c, m0d)),                \
                     fmaxf(m0e, s0[15]));                                    \
    tm = fmaxf(tm, __shfl_xor(tm, 32));                                      \
    if (__any(tm > mrun + 11.5f)) {                                          \
      float mnew = fmaxf(mrun, tm);                                          \
      float scl = fexp2(mrun - mnew);                                        \
      mrun = mnew;                                                           \
      lrun *= scl;                                                           \
      _Pragma("unroll")                                                      \
      for (int r = 0; r < 16; r++) {                                         \
        float sq = __shfl(scl, (r & 3) + 8 * (r >> 2) + 4 * hi);             \
        acc0[r] *= sq;                                                       \
        acc1[r] *= sq;                                                       \
      }                                                                      \
    }                                                                        \
    float ts = 0.f;                                                          \
    u32 P2[4][2];                                                            \
    _Pragma("unroll")                                                        \
    for (int s2 = 0; s2 < 4; s2++)                                           \
      _Pragma("unroll")                                                      \
      for (int c2 = 0; c2 < 2; c2++) {                                       \
        float a = fexp2(s0[4 * s2 + 2 * c2] - mrun);                         \
        float bb = fexp2(s0[4 * s2 + 2 * c2 + 1] - mrun);                    \
        ts += a + bb;                                                        \
        P2[s2][c2] = __builtin_bit_cast(u32, __builtin_amdgcn_cvt_pkrtz(a, bb)); \
      }                                                                      \
    ts += __shfl_xor(ts, 32);                                                \
    lrun += ts;                                                              \
    _Pragma("unroll")                                                        \
    for (int s = 0; s < 2; s++) {                                            \
      int x0 = (int)P2[2 * s][0], y0 = (int)P2[2 * s + 1][0];                \
      int x1 = (int)P2[2 * s][1], y1 = (int)P2[2 * s + 1][1];                \
      asm("v_permlane32_swap_b32 %0, %1" : "+v"(x0), "+v"(y0));              \
      asm("v_permlane32_swap_b32 %0, %1" : "+v"(x1), "+v"(y1));              \
      f16x8 pa = __builtin_bit_cast(f16x8, (i32x4){x0, x1, y0, y1});         \
      __builtin_amdgcn_s_setprio(1);                                         \
      {                                                                      \
        f16x8 vb = *(const f16x8*)(Vc + vr0 + vo[s]);                        \
        acc0 = __builtin_amdgcn_mfma_f32_32x32x16_f16(pa, vb, acc0, 0, 0, 0);\
      }                                                                      \
      {                                                                      \
        f16x8 vb = *(const f16x8*)(Vc + vr1 + vo[s]);                        \
        acc1 = __builtin_amdgcn_mfma_f32_32x32x16_f16(pa, vb, acc1, 0, 0, 0);\
      }                                                                      \
      __builtin_amdgcn_s_setprio(0);                                         \
    }                                                                        \
  } while (0)

  STAGE(0);                            // parity-local tile 0
  __syncthreads();
  for (int i2 = 0; i2 < 18; i2++) {    // 36 tiles per parity, x2 unrolled
    STAGE(1);
    COMPUTE(0);
    __syncthreads();
    if (i2 < 17) STAGE(0);
    COMPUTE(1);
    __syncthreads();
  }

  // ---- in-block merge of the two KV-parity partials, then epilogue ----
  float* sf = (float*)smem;            // O stash: qh*2048 + (dblk*16+r)*64 + lane
  if (tp) {
#pragma unroll
    for (int r = 0; r < 16; r++) {
      sf[qh * 2048 + r * 64 + lane] = acc0[r];
      sf[qh * 2048 + (16 + r) * 64 + lane] = acc1[r];
    }
    if (lane < 32) {
      sf[8192 + qh * 64 + l31] = mrun;
      sf[8192 + qh * 64 + 32 + l31] = lrun;
    }
  }
  __syncthreads();
  if (!tp) {
    float mb = sf[8192 + qh * 64 + l31];
    float lb = sf[8192 + qh * 64 + 32 + l31];
    float M = fmaxf(mrun, mb);
    float fa = fexp2(mrun - M), fb = fexp2(mb - M);
    float linv = 1.0f / (lrun * fa + lb * fb);
    fa *= linv; fb *= linv;
    float faq[16], fbq[16];
#pragma unroll
    for (int r = 0; r < 16; r++) {
      int qloc = (r & 3) + 8 * (r >> 2) + 4 * hi;
      faq[r] = __shfl(fa, qloc);
      fbq[r] = __shfl(fb, qloc);
    }
    size_t outbase = ((size_t)b * CCH + h * DH) * NSP;
#pragma unroll
    for (int dblk = 0; dblk < 2; dblk++) {
      int d = dblk * 32 + l31;
      float g = gamma[h * DH + d];
      float* orow = out + outbase + (size_t)d * NSP + q0w;
#pragma unroll
      for (int s2 = 0; s2 < 4; s2++) {
        int n = 8 * s2 + 4 * hi;
        f32x4 o;
#pragma unroll
        for (int t = 0; t < 4; t++) {
          int r = 4 * s2 + t;
          float oa = dblk ? acc1[r] : acc0[r];
          float ob = sf[qh * 2048 + (dblk * 16 + r) * 64 + lane];
          o[t] = (oa * faq[r] + ob * fbq[r]) * g;
        }
        f32x4 sc = *(const f32x4*)(orow + n);
        *(f32x4*)(orow + n) = o + sc;
      }
    }
  }
#undef STAGE
#undef COMPUTE
}

extern "C" void kernel_launch(void* const* d_in, const int* in_sizes, int n_in,
                              void* d_out, int out_size, void* d_ws, size_t ws_size,
                              hipStream_t stream) {
  const float* x     = (const float*)d_in[0];
  const float* Wq    = (const float*)d_in[1];
  const float* Wk    = (const float*)d_in[2];
  const float* Wv    = (const float*)d_in[3];
  const float* Wsc   = (const float*)d_in[4];
  const float* gamma = (const float*)d_in[5];
  float* out = (float*)d_out;

  u16* xT   = (u16*)d_ws;                               // 4*2304*512
  u16* Wall = xT + (size_t)BSZ * NSP * CCH;             // 4*512*512
  u16* Qw   = Wall + (size_t)4 * CCH * CCH;             // 4*8*2304*64
  u16* Kw   = Qw + (size_t)BSZ * CCH * NSP;
  u16* Vw   = Kw + (size_t)BSZ * CCH * NSP;

  hipLaunchKernelGGL(k_cvt, dim3(1024 + BSZ * (CCH / 64) * (NSP / 64)), dim3(256), 0, stream,
                     Wq, Wk, Wv, Wsc, Wall, x, xT);
  hipLaunchKernelGGL(k_proj, dim3(NSP / 128, CCH / 128, BSZ * 4), dim3(256), 0, stream,
                     Wall, xT, Qw, Kw, Vw, out);
  hipLaunchKernelGGL(k_attn, dim3(BSZ * HEADS, NSP / 128), dim3(512), 0, stream,
                     Qw, Kw, Vw, gamma, out);
}

// Round 19
// 137.917 us; speedup vs baseline: 1.0611x; 1.0611x over previous
//
#include <hip/hip_runtime.h>

#define HEADS 8
static constexpr int BSZ = 4;
static constexpr int CCH = 512;
static constexpr int NSP = 2304;   // 48*48
static constexpr int DH  = 64;     // head dim

typedef _Float16 f16x8 __attribute__((ext_vector_type(8)));
typedef float f32x4 __attribute__((ext_vector_type(4)));
typedef float f32x16 __attribute__((ext_vector_type(16)));
typedef int i32x4 __attribute__((ext_vector_type(4)));
typedef unsigned short u16;
typedef unsigned int u32;

__device__ __forceinline__ u16 f2h(float f) {
  _Float16 h = (_Float16)f;
  return __builtin_bit_cast(u16, h);
}

__device__ __forceinline__ float fexp2(float x) {
  return __builtin_amdgcn_exp2f(x);
}

__device__ __forceinline__ void gl_lds16(const void* g, void* l) {
  __builtin_amdgcn_global_load_lds(
      (const __attribute__((address_space(1))) u32*)g,
      (__attribute__((address_space(3))) u32*)l, 16, 0, 0);
}

// ------ kernel 1: fused input conversion (W fp32->fp16, x transpose) ----
// blocks [0,1024): weight convert (wsel = gid>>8). blocks [1024,2176):
// x (b,c,n) fp32 -> xT (b,n,c) fp16 via 64x64 LDS transpose tile.
// Branch is block-uniform -> __syncthreads in the else-path is safe.
__global__ __launch_bounds__(256) void k_cvt(const float* __restrict__ w0,
    const float* __restrict__ w1, const float* __restrict__ w2,
    const float* __restrict__ w3, u16* __restrict__ Wall,
    const float* __restrict__ x, u16* __restrict__ xT) {
  __shared__ u16 t[64][66];
  int gid = blockIdx.x;
  if (gid < 1024) {
    int wsel = gid >> 8, bx = gid & 255;
    const float* src = wsel == 0 ? w0 : wsel == 1 ? w1 : wsel == 2 ? w2 : w3;
    int i = (bx * 256 + threadIdx.x) * 4;
    float4 v = *(const float4*)(src + i);
    ushort4 o;
    o.x = f2h(v.x); o.y = f2h(v.y); o.z = f2h(v.z); o.w = f2h(v.w);
    *(ushort4*)(Wall + (size_t)wsel * CCH * CCH + i) = o;
  } else {
    int g2 = gid - 1024;
    int b = g2 / 288, rem = g2 % 288;
    int c0 = (rem / 36) * 64, n0 = (rem % 36) * 64;
    int col = threadIdx.x & 63, rb = threadIdx.x >> 6;
#pragma unroll
    for (int rr = 0; rr < 16; rr++) {
      int r = rr * 4 + rb;  // c-local
      t[r][col] = f2h(x[((size_t)b * CCH + c0 + r) * NSP + n0 + col]);
    }
    __syncthreads();
#pragma unroll
    for (int rr = 0; rr < 16; rr++) {
      int r = rr * 4 + rb;  // n-local
      xT[((size_t)b * NSP + n0 + r) * CCH + c0 + col] = t[col][r];
    }
  }
}

// ------- kernel 2: fused 4-way projection GEMM (Wq/Wk/Wv/Wsc) ----------
// R17 version (BK=64, serial 2-barrier staging loop). R18's BK=32 dbuf
// regressed -7us: halved MFMA/barrier + doubled barrier count outweighed
// the latency overlap; cross-block concurrency (9 blocks/CU) already
// covers staging latency here.
// Q is pre-scaled by log2(e) so attention softmax can use raw exp2.
__global__ __launch_bounds__(256) void k_proj(const u16* __restrict__ Wall,
    const u16* __restrict__ xT, u16* __restrict__ Qo, u16* __restrict__ Ko,
    u16* __restrict__ Vo, float* __restrict__ SCo) {
  __shared__ u16 smem[17408];          // A[128][64] | B[128][64]; reused as stash[128][136]
  u16* At = smem;
  u16* Bt = smem + 8192;
  int z = blockIdx.z, b = z >> 2, wsel = z & 3;
  int o0 = blockIdx.y * 128, n0 = blockIdx.x * 128;
  int tid = threadIdx.x, lane = tid & 63, wv = tid >> 6;
  int wr = wv >> 1, wc = wv & 1;
  const u16* Asrc = Wall + (size_t)wsel * CCH * CCH + (size_t)o0 * CCH;
  const u16* Bsrc = xT + ((size_t)b * NSP + n0) * CCH;
  f32x4 acc[4][4] = {};
  for (int kc = 0; kc < CCH; kc += 64) {
    __syncthreads();
#pragma unroll
    for (int i = 0; i < 4; i++) {
      int ch = (wv * 4 + i) * 64 + lane;
      int row = ch >> 3, cc = ch & 7;
      gl_lds16(Asrc + (size_t)row * CCH + kc + ((cc ^ (row & 7)) << 3), At + (wv * 4 + i) * 512);
      gl_lds16(Bsrc + (size_t)row * CCH + kc + ((cc ^ (row & 7)) << 3), Bt + (wv * 4 + i) * 512);
    }
    __syncthreads();
#pragma unroll
    for (int ks = 0; ks < 2; ks++) {
      f16x8 af[4], bfr[4];
#pragma unroll
      for (int f = 0; f < 4; f++) {
        int orow = wr * 64 + f * 16 + (lane & 15);
        int nrow = wc * 64 + f * 16 + (lane & 15);
        int k8 = (lane >> 4) + ks * 4;
        af[f]  = *(const f16x8*)(At + orow * 64 + ((k8 ^ (orow & 7)) << 3));
        bfr[f] = *(const f16x8*)(Bt + nrow * 64 + ((k8 ^ (nrow & 7)) << 3));
      }
#pragma unroll
      for (int i = 0; i < 4; i++)
#pragma unroll
        for (int j = 0; j < 4; j++)
          acc[i][j] = __builtin_amdgcn_mfma_f32_16x16x32_f16(af[i], bfr[j], acc[i][j], 0, 0, 0);
    }
  }
  if (wsel >= 2) {
#pragma unroll
    for (int i = 0; i < 4; i++)
#pragma unroll
      for (int j = 0; j < 4; j++)
#pragma unroll
        for (int r = 0; r < 4; r++) {
          int o = o0 + wr * 64 + i * 16 + ((lane >> 4) << 2) + r;
          int n = n0 + wc * 64 + j * 16 + (lane & 15);
          size_t idx = ((size_t)b * CCH + o) * NSP + n;
          if (wsel == 3) SCo[idx] = acc[i][j][r];
          else           Vo[idx]  = f2h(acc[i][j][r]);
        }
  } else {
    __syncthreads();
    u16* stash = smem;  // [128 n][136 o]
    float qs = (wsel == 0) ? 1.4426950408889634f : 1.0f;  // fold log2e into Q
#pragma unroll
    for (int i = 0; i < 4; i++)
#pragma unroll
      for (int j = 0; j < 4; j++)
#pragma unroll
        for (int r = 0; r < 4; r++) {
          int ol = wr * 64 + i * 16 + ((lane >> 4) << 2) + r;
          int nl = wc * 64 + j * 16 + (lane & 15);
          stash[nl * 136 + ol] = f2h(acc[i][j][r] * qs);
        }
    __syncthreads();
    u16* dst = wsel ? Ko : Qo;
    int hl = tid >> 7, nn = tid & 127;
    int h = (o0 >> 6) + hl;
    size_t base = ((size_t)(b * HEADS + h) * NSP + n0 + nn) * DH;
#pragma unroll
    for (int c2 = 0; c2 < 8; c2++)
      *(int4*)(dst + base + c2 * 8) = *(const int4*)(stash + nn * 136 + hl * 64 + c2 * 8);
  }
}

// ------------------- kernel 3: flash attention + epilogue ---------------
// R12/R15/R17 configuration EXACTLY (93.7-94.0 us, reproduced 4x). Scheduler
// sweet spot: 512-thr blocks, 8 waves = 4 q-subtiles x 2 KV-parities;
// 32-row tiles double-buffered per parity in 32KB LDS; in-block merge;
// bh-major grid pins each head's KV to one XCD (FETCH 90->26MB).
// NO launch_bounds waves-per-EU arg (caps VGPRs + residency: R4/R6/R7).
__global__ __launch_bounds__(512) void k_attn(const u16* __restrict__ Qw,
    const u16* __restrict__ Kw, const u16* __restrict__ Vw,
    const float* __restrict__ gamma, float* __restrict__ out) {
  __shared__ u16 smem[17408];          // 32KB staging [tp][buf][K2048|V2048] + 2KB merge m/l
  int bh = blockIdx.x, qt = blockIdx.y;
  int b = bh >> 3, h = bh & 7;
  int tid = threadIdx.x, lane = tid & 63, wv = tid >> 6;
  int l31 = lane & 31, hi = lane >> 5;
  int qh = wv & 3, tp = wv >> 2;
  int gid = tid & 255;                 // id within parity group
  int q0w = qt * 128 + qh * 32;
  const u16* Ksrc = Kw + (size_t)bh * NSP * DH;
  const u16* Vsrc = Vw + ((size_t)b * CCH + h * DH) * NSP;
  u16* PB = smem + tp * 8192;          // this parity's staging (2 bufs x 4096)

  // --- staging pointers: 1 K-chunk + 1 V-chunk per thread, advance 64 rows ---
  int mk = gid >> 3, pk = gid & 7;
  const u16* kc = Ksrc + (tp * 32 + mk) * DH + ((pk ^ (mk & 7)) << 3);
  int dv = gid >> 2, pv = gid & 3;
  const u16* vc = Vsrc + (size_t)dv * NSP + tp * 32 + ((pv ^ ((dv >> 1) & 3)) << 3);

#define STAGE(c)                                   \
  do {                                             \
    gl_lds16(kc, PB + (c) * 4096 + gid * 8);       \
    gl_lds16(vc, PB + (c) * 4096 + 2048 + gid * 8);\
    kc += 64 * DH;                                 \
    vc += 64;                                      \
  } while (0)

  // --- hoisted LDS read offsets (u16 units) ---
  int kswz = l31 & 7, vswz = (l31 >> 1) & 3;
  int kro = l31 * 64;
  int ko[4], vo[2];
#pragma unroll
  for (int kd = 0; kd < 4; kd++) ko[kd] = ((2 * kd + hi) ^ kswz) << 3;
#pragma unroll
  for (int s = 0; s < 2; s++) vo[s] = ((2 * s + hi) ^ vswz) << 3;
  int vr0 = l31 * 32, vr1 = (32 + l31) * 32;

  // Q B-frags: lane holds Q[q0w + l31][d = 16*kd + 8*hi + j]  (pre-scaled by log2e)
  f16x8 qf[4];
  const u16* Qbase = Qw + ((size_t)bh * NSP + q0w + l31) * DH + hi * 8;
#pragma unroll
  for (int kd = 0; kd < 4; kd++)
    qf[kd] = *(const f16x8*)(Qbase + kd * 16);

  float mrun = -1e30f, lrun = 0.f;
  f32x16 acc0 = {}, acc1 = {};   // lane: d = dblk*32+l31, q(r) = (r&3)+8*(r>>2)+4*hi

#define COMPUTE(c)                                                           \
  do {                                                                       \
    const u16* Kc = PB + (c) * 4096;                                         \
    const u16* Vc = Kc + 2048;                                               \
    f32x16 s0 = {};                                                          \
    __builtin_amdgcn_s_setprio(1);                                           \
    _Pragma("unroll")                                                        \
    for (int kd = 0; kd < 4; kd++) {                                         \
      f16x8 k0 = *(const f16x8*)(Kc + kro + ko[kd]);                         \
      s0 = __builtin_amdgcn_mfma_f32_32x32x16_f16(k0, qf[kd], s0, 0, 0, 0);  \
    }                                                                        \
    __builtin_amdgcn_s_setprio(0);                                           \
    float m0a = fmaxf(fmaxf(s0[0], s0[1]), s0[2]);                           \
    float m0b = fmaxf(fmaxf(s0[3], s0[4]), s0[5]);                           \
    float m0c = fmaxf(fmaxf(s0[6], s0[7]), s0[8]);                           \
    float m0d = fmaxf(fmaxf(s0[9], s0[10]), s0[11]);                         \
    float m0e = fmaxf(fmaxf(s0[12], s0[13]), s0[14]);                        \
    float tm = fmaxf(fmaxf(fmaxf(m0a, m0b), fmaxf(m0c, m0d)),                \
                     fmaxf(m0e, s0[15]));                                    \
    tm = fmaxf(tm, __shfl_xor(tm, 32));                                      \
    if (__any(tm > mrun + 11.5f)) {                                          \
      float mnew = fmaxf(mrun, tm);                                          \
      float scl = fexp2(mrun - mnew);                                        \
      mrun = mnew;                                                           \
      lrun *= scl;                                                           \
      _Pragma("unroll")                                                      \
      for (int r = 0; r < 16; r++) {                                         \
        float sq = __shfl(scl, (r & 3) + 8 * (r >> 2) + 4 * hi);             \
        acc0[r] *= sq;                                                       \
        acc1[r] *= sq;                                                       \
      }                                                                      \
    }                                                                        \
    float ts = 0.f;                                                          \
    u32 P2[4][2];                                                            \
    _Pragma("unroll")                                                        \
    for (int s2 = 0; s2 < 4; s2++)                                           \
      _Pragma("unroll")                                                      \
      for (int c2 = 0; c2 < 2; c2++) {                                       \
        float a = fexp2(s0[4 * s2 + 2 * c2] - mrun);                         \
        float bb = fexp2(s0[4 * s2 + 2 * c2 + 1] - mrun);                    \
        ts += a + bb;                                                        \
        P2[s2][c2] = __builtin_bit_cast(u32, __builtin_amdgcn_cvt_pkrtz(a, bb)); \
      }                                                                      \
    ts += __shfl_xor(ts, 32);                                                \
    lrun += ts;                                                              \
    _Pragma("unroll")                                                        \
    for (int s = 0; s < 2; s++) {                                            \
      int x0 = (int)P2[2 * s][0], y0 = (int)P2[2 * s + 1][0];                \
      int x1 = (int)P2[2 * s][1], y1 = (int)P2[2 * s + 1][1];                \
      asm("v_permlane32_swap_b32 %0, %1" : "+v"(x0), "+v"(y0));              \
      asm("v_permlane32_swap_b32 %0, %1" : "+v"(x1), "+v"(y1));              \
      f16x8 pa = __builtin_bit_cast(f16x8, (i32x4){x0, x1, y0, y1});         \
      __builtin_amdgcn_s_setprio(1);                                         \
      {                                                                      \
        f16x8 vb = *(const f16x8*)(Vc + vr0 + vo[s]);                        \
        acc0 = __builtin_amdgcn_mfma_f32_32x32x16_f16(pa, vb, acc0, 0, 0, 0);\
      }                                                                      \
      {                                                                      \
        f16x8 vb = *(const f16x8*)(Vc + vr1 + vo[s]);                        \
        acc1 = __builtin_amdgcn_mfma_f32_32x32x16_f16(pa, vb, acc1, 0, 0, 0);\
      }                                                                      \
      __builtin_amdgcn_s_setprio(0);                                         \
    }                                                                        \
  } while (0)

  STAGE(0);                            // parity-local tile 0
  __syncthreads();
  for (int i2 = 0; i2 < 18; i2++) {    // 36 tiles per parity, x2 unrolled
    STAGE(1);
    COMPUTE(0);
    __syncthreads();
    if (i2 < 17) STAGE(0);
    COMPUTE(1);
    __syncthreads();
  }

  // ---- in-block merge of the two KV-parity partials, then epilogue ----
  float* sf = (float*)smem;            // O stash: qh*2048 + (dblk*16+r)*64 + lane
  if (tp) {
#pragma unroll
    for (int r = 0; r < 16; r++) {
      sf[qh * 2048 + r * 64 + lane] = acc0[r];
      sf[qh * 2048 + (16 + r) * 64 + lane] = acc1[r];
    }
    if (lane < 32) {
      sf[8192 + qh * 64 + l31] = mrun;
      sf[8192 + qh * 64 + 32 + l31] = lrun;
    }
  }
  __syncthreads();
  if (!tp) {
    float mb = sf[8192 + qh * 64 + l31];
    float lb = sf[8192 + qh * 64 + 32 + l31];
    float M = fmaxf(mrun, mb);
    float fa = fexp2(mrun - M), fb = fexp2(mb - M);
    float linv = 1.0f / (lrun * fa + lb * fb);
    fa *= linv; fb *= linv;
    float faq[16], fbq[16];
#pragma unroll
    for (int r = 0; r < 16; r++) {
      int qloc = (r & 3) + 8 * (r >> 2) + 4 * hi;
      faq[r] = __shfl(fa, qloc);
      fbq[r] = __shfl(fb, qloc);
    }
    size_t outbase = ((size_t)b * CCH + h * DH) * NSP;
#pragma unroll
    for (int dblk = 0; dblk < 2; dblk++) {
      int d = dblk * 32 + l31;
      float g = gamma[h * DH + d];
      float* orow = out + outbase + (size_t)d * NSP + q0w;
#pragma unroll
      for (int s2 = 0; s2 < 4; s2++) {
        int n = 8 * s2 + 4 * hi;
        f32x4 o;
#pragma unroll
        for (int t = 0; t < 4; t++) {
          int r = 4 * s2 + t;
          float oa = dblk ? acc1[r] : acc0[r];
          float ob = sf[qh * 2048 + (dblk * 16 + r) * 64 + lane];
          o[t] = (oa * faq[r] + ob * fbq[r]) * g;
        }
        f32x4 sc = *(const f32x4*)(orow + n);
        *(f32x4*)(orow + n) = o + sc;
      }
    }
  }
#undef STAGE
#undef COMPUTE
}

extern "C" void kernel_launch(void* const* d_in, const int* in_sizes, int n_in,
                              void* d_out, int out_size, void* d_ws, size_t ws_size,
                              hipStream_t stream) {
  const float* x     = (const float*)d_in[0];
  const float* Wq    = (const float*)d_in[1];
  const float* Wk    = (const float*)d_in[2];
  const float* Wv    = (const float*)d_in[3];
  const float* Wsc   = (const float*)d_in[4];
  const float* gamma = (const float*)d_in[5];
  float* out = (float*)d_out;

  u16* xT   = (u16*)d_ws;                               // 4*2304*512
  u16* Wall = xT + (size_t)BSZ * NSP * CCH;             // 4*512*512
  u16* Qw   = Wall + (size_t)4 * CCH * CCH;             // 4*8*2304*64
  u16* Kw   = Qw + (size_t)BSZ * CCH * NSP;
  u16* Vw   = Kw + (size_t)BSZ * CCH * NSP;

  hipLaunchKernelGGL(k_cvt, dim3(1024 + BSZ * (CCH / 64) * (NSP / 64)), dim3(256), 0, stream,
                     Wq, Wk, Wv, Wsc, Wall, x, xT);
  hipLaunchKernelGGL(k_proj, dim3(NSP / 128, CCH / 128, BSZ * 4), dim3(256), 0, stream,
                     Wall, xT, Qw, Kw, Vw, out);
  hipLaunchKernelGGL(k_attn, dim3(BSZ * HEADS, NSP / 128), dim3(512), 0, stream,
                     Qw, Kw, Vw, gamma, out);
}